// Round 1
// 2560.310 us; speedup vs baseline: 1.1621x; 1.1621x over previous
//
#include <hip/hip_runtime.h>

// Problem constants
#define BATCH 4
#define SEQ   2048
#define HIDC  2048
#define NHC   16
#define DKC   128
#define DVC   128
#define MROWS (BATCH * SEQ)   // 8192
#define NDC   2048            // NH*DK = NH*DV

typedef __bf16 bf16_t;
typedef __bf16 bf16x8 __attribute__((ext_vector_type(8)));
typedef float  floatx4 __attribute__((ext_vector_type(4)));

__device__ __forceinline__ float sigf(float z) { return 1.f / (1.f + __expf(-z)); }

// 16-lane sum reduce, entirely on the VALU pipe (DPP, no LDS):
// xor1,xor2 via quad_perm; xor4 via ROW_HALF_MIRROR (valid: values are
// quad-uniform after xor1/2); xor8 via ROW_MIRROR (valid: 8-group-uniform).
__device__ __forceinline__ float red16(float x) {
  int a;
  a = __float_as_int(x);
  x += __int_as_float(__builtin_amdgcn_update_dpp(a, a, 0xB1, 0xF, 0xF, true));   // xor 1
  a = __float_as_int(x);
  x += __int_as_float(__builtin_amdgcn_update_dpp(a, a, 0x4E, 0xF, 0xF, true));   // xor 2
  a = __float_as_int(x);
  x += __int_as_float(__builtin_amdgcn_update_dpp(a, a, 0x141, 0xF, 0xF, true));  // row_half_mirror
  a = __float_as_int(x);
  x += __int_as_float(__builtin_amdgcn_update_dpp(a, a, 0x140, 0xF, 0xF, true));  // row_mirror
  return x;
}

__device__ __forceinline__ float dot8(const float* a, const float* b) {
  float d0 = 0.f, d1 = 0.f;
#pragma unroll
  for (int i = 0; i < 4; ++i) {
    d0 += a[i] * b[i];
    d1 += a[4 + i] * b[4 + i];
  }
  return d0 + d1;
}

#define LD8(dst, ptr)                                \
  {                                                  \
    *(float4*)&dst[0] = ((const float4*)(ptr))[0];   \
    *(float4*)&dst[4] = ((const float4*)(ptr))[1];   \
  }

// ---------------------------------------------------------------------------
// fp32 -> bf16 convert (8 elems/thread)
// ---------------------------------------------------------------------------
__global__ __launch_bounds__(256) void f2b_k(const float* __restrict__ src,
                                             bf16_t* __restrict__ dst) {
  size_t i = ((size_t)blockIdx.x * 256 + threadIdx.x) * 8;
  float4 a = *(const float4*)(src + i);
  float4 b = *(const float4*)(src + i + 4);
  bf16_t tmp[8] = {(bf16_t)a.x, (bf16_t)a.y, (bf16_t)a.z, (bf16_t)a.w,
                   (bf16_t)b.x, (bf16_t)b.y, (bf16_t)b.z, (bf16_t)b.w};
  *(bf16x8*)(dst + i) = *(bf16x8*)tmp;
}

// ---------------------------------------------------------------------------
// Transpose+convert 2048x2048: Wt[n][k] = bf16(W[k][n]), W fp32
// ---------------------------------------------------------------------------
__global__ __launch_bounds__(256) void transpose_k(const float* __restrict__ W,
                                                   bf16_t* __restrict__ Wt) {
  __shared__ float tile[32][33];
  int kb = blockIdx.x * 32, nb = blockIdx.y * 32;
  int tx = threadIdx.x, ty = threadIdx.y;  // (32,8)
#pragma unroll
  for (int r = 0; r < 4; ++r)
    tile[ty + 8 * r][tx] = W[(size_t)(kb + ty + 8 * r) * 2048 + nb + tx];
  __syncthreads();
#pragma unroll
  for (int r = 0; r < 4; ++r)
    Wt[(size_t)(nb + ty + 8 * r) * 2048 + kb + tx] = (bf16_t)tile[tx][ty + 8 * r];
}

// ---------------------------------------------------------------------------
// Transpose Wb 2048x16 -> Wbt 16x2048 (fp32), one-time 128KB shuffle.
// ---------------------------------------------------------------------------
__global__ __launch_bounds__(256) void wbt_k(const float* __restrict__ Wb,
                                             float* __restrict__ Wbt) {
  int idx = blockIdx.x * 256 + threadIdx.x;  // < 16*2048
  int n = idx >> 11;
  int j = idx & 2047;
  Wbt[idx] = Wb[(size_t)j * NHC + n];
}

// ---------------------------------------------------------------------------
// bf16 MFMA GEMM (NT): C[M][N] = A[M][K] * Bt[N][K]^T, fp32 accumulate.
// 128x128 tile, 4 waves each 64x64 (4x4 of 16x16x32 mfma), BK=32.
// EP: 0 = plain store, 1 = sigmoid, 2 = sigmoid(acc + bias[col]).
// ---------------------------------------------------------------------------
template <typename OT, int EP>
__global__ __launch_bounds__(256) void gemm_nt(const bf16_t* __restrict__ A,
                                               const bf16_t* __restrict__ Bt,
                                               OT* __restrict__ C,
                                               const float* __restrict__ bias,
                                               int N, int K,
                                               int amap, int cmap, int cOff, int scShift) {
  __shared__ bf16_t As[128][40];  // +8 pad breaks pow2 bank stride
  __shared__ bf16_t Bs[128][40];
  const int tid = threadIdx.x;
  const int m0 = blockIdx.x * 128;
  const int n0 = blockIdx.y * 128;
  const int scMask = (1 << scShift) - 1;
  const int ga = amap ? (((m0 >> scShift) << 11) + cOff + (m0 & scMask)) : m0;
  const int gc = cmap ? (((m0 >> scShift) << 11) + cOff + (m0 & scMask)) : m0;
  const int wave = tid >> 6;
  const int lane = tid & 63;
  const int wm = (wave >> 1) * 64;
  const int wn = (wave & 1) * 64;
  const int qd = lane >> 4;    // quad 0..3
  const int l16 = lane & 15;
  const int ar = tid >> 1;             // staging row 0..127
  const int ac = (tid & 1) * 16;       // staging col 0 or 16

  const floatx4 fzero = {0.f, 0.f, 0.f, 0.f};
  floatx4 acc[4][4];
#pragma unroll
  for (int i = 0; i < 4; ++i)
#pragma unroll
    for (int j = 0; j < 4; ++j) acc[i][j] = fzero;

  const bf16_t* ag = A + (size_t)(ga + ar) * K + ac;
  const bf16_t* bg = Bt + (size_t)(n0 + ar) * K + ac;

  for (int k0 = 0; k0 < K; k0 += 32) {
    bf16x8 a0 = *(const bf16x8*)(ag + k0);
    bf16x8 a1 = *(const bf16x8*)(ag + k0 + 8);
    bf16x8 b0 = *(const bf16x8*)(bg + k0);
    bf16x8 b1 = *(const bf16x8*)(bg + k0 + 8);
    *(bf16x8*)&As[ar][ac] = a0;
    *(bf16x8*)&As[ar][ac + 8] = a1;
    *(bf16x8*)&Bs[ar][ac] = b0;
    *(bf16x8*)&Bs[ar][ac + 8] = b1;
    __syncthreads();
    bf16x8 afr[4], bfr[4];
#pragma unroll
    for (int i = 0; i < 4; ++i)
      afr[i] = *(const bf16x8*)&As[wm + 16 * i + l16][qd * 8];
#pragma unroll
    for (int j = 0; j < 4; ++j)
      bfr[j] = *(const bf16x8*)&Bs[wn + 16 * j + l16][qd * 8];
#pragma unroll
    for (int i = 0; i < 4; ++i)
#pragma unroll
      for (int j = 0; j < 4; ++j)
        acc[i][j] = __builtin_amdgcn_mfma_f32_16x16x32_bf16(afr[i], bfr[j], acc[i][j], 0, 0, 0);
    __syncthreads();
  }
  // C/D layout: col(N) = lane&15, row(M) = (lane>>4)*4 + reg  [measured m89]
#pragma unroll
  for (int i = 0; i < 4; ++i)
#pragma unroll
    for (int j = 0; j < 4; ++j)
#pragma unroll
      for (int r = 0; r < 4; ++r) {
        int mm = gc + wm + 16 * i + qd * 4 + r;
        int nn = n0 + wn + 16 * j + l16;
        float val = acc[i][j][r];
        if (EP == 2) val = sigf(val + bias[nn]);
        else if (EP == 1) val = sigf(val);
        C[(size_t)mm * N + nn] = (OT)val;
      }
}

// ---------------------------------------------------------------------------
// beta = sigmoid(x @ Wb + bb)   x:[8192,2048] fp32, Wbt:[16,2048] fp32.
// 4 rows/block staged in LDS; wave w computes heads n = w,w+4,w+8,w+12 for
// all 4 rows with coalesced float4 reads of Wbt (L2-resident, contiguous).
// ---------------------------------------------------------------------------
__global__ __launch_bounds__(256) void beta_k(const float* __restrict__ x,
                                              const float* __restrict__ Wbt,
                                              const float* __restrict__ bb,
                                              float* __restrict__ beta) {
  __shared__ float xs[4][HIDC];
  const int row0 = blockIdx.x * 4;
  for (int i = threadIdx.x; i < 4 * (HIDC / 4); i += 256) {
    int r = i >> 9;          // /512
    int j = i & 511;
    ((float4*)xs[r])[j] = ((const float4*)(x + (size_t)(row0 + r) * HIDC))[j];
  }
  __syncthreads();
  const int wave = threadIdx.x >> 6, lane = threadIdx.x & 63;
#pragma unroll
  for (int nb = 0; nb < 4; ++nb) {
    const int n = wave + nb * 4;
    float acc0 = 0.f, acc1 = 0.f, acc2 = 0.f, acc3 = 0.f;
    const float4* wrow = (const float4*)(Wbt + (size_t)n * HIDC);
    for (int j = lane; j < HIDC / 4; j += 64) {
      float4 wv = wrow[j];
      float4 x0 = ((const float4*)xs[0])[j];
      float4 x1 = ((const float4*)xs[1])[j];
      float4 x2 = ((const float4*)xs[2])[j];
      float4 x3 = ((const float4*)xs[3])[j];
      acc0 += wv.x * x0.x + wv.y * x0.y + wv.z * x0.z + wv.w * x0.w;
      acc1 += wv.x * x1.x + wv.y * x1.y + wv.z * x1.z + wv.w * x1.w;
      acc2 += wv.x * x2.x + wv.y * x2.y + wv.z * x2.z + wv.w * x2.w;
      acc3 += wv.x * x3.x + wv.y * x3.y + wv.z * x3.z + wv.w * x3.w;
    }
    float accs[4] = {acc0, acc1, acc2, acc3};
#pragma unroll
    for (int r = 0; r < 4; ++r) {
      float s = accs[r];
#pragma unroll
      for (int off = 32; off; off >>= 1) s += __shfl_xor(s, off);
      if (lane == 0) beta[(size_t)(row0 + r) * NHC + n] = sigf(s + bb[n]);
    }
  }
}

// ---------------------------------------------------------------------------
// fused 3x causal depthwise conv (K=4) + bias + SiLU (*scale for k).
// ---------------------------------------------------------------------------
__global__ void conv3_k(const float* __restrict__ Yq, const float* __restrict__ Yk,
                        const float* __restrict__ Yv,
                        const float* __restrict__ tq, const float* __restrict__ tk,
                        const float* __restrict__ tv,
                        const float* __restrict__ cqw, const float* __restrict__ cqb,
                        const float* __restrict__ ckw, const float* __restrict__ ckb,
                        const float* __restrict__ cvw, const float* __restrict__ cvb,
                        float* __restrict__ qb, float* __restrict__ kb,
                        float* __restrict__ vb, int cOff, int scShift) {
  size_t idx = (size_t)blockIdx.x * blockDim.x + threadIdx.x;
  int ch = (int)(idx & 2047);
  int mloc = (int)(idx >> 11);
  int sloc = mloc & ((1 << scShift) - 1);
  int b = mloc >> scShift;
  int sg = cOff + sloc;
  float4 wq = *(const float4*)(cqw + ch * 4);  // .x=w0 .y=w1 .z=w2 .w=w3
  float4 wk = *(const float4*)(ckw + ch * 4);
  float4 wv = *(const float4*)(cvw + ch * 4);
  float aq = cqb[ch] + wq.w * Yq[idx];
  float ak = ckb[ch] + wk.w * Yk[idx];
  float av = cvb[ch] + wv.w * Yv[idx];
  if (sg >= 1) {
    bool in = sloc >= 1;
    size_t iy = idx - 2048;
    size_t it = (size_t)(b * 3 + 2 + sloc) * 2048 + ch;
    aq += wq.z * (in ? Yq[iy] : tq[it]);
    ak += wk.z * (in ? Yk[iy] : tk[it]);
    av += wv.z * (in ? Yv[iy] : tv[it]);
  }
  if (sg >= 2) {
    bool in = sloc >= 2;
    size_t iy = idx - 2 * 2048;
    size_t it = (size_t)(b * 3 + 1 + sloc) * 2048 + ch;
    aq += wq.y * (in ? Yq[iy] : tq[it]);
    ak += wk.y * (in ? Yk[iy] : tk[it]);
    av += wv.y * (in ? Yv[iy] : tv[it]);
  }
  if (sg >= 3) {
    bool in = sloc >= 3;
    size_t iy = idx - 3 * 2048;
    size_t it = (size_t)(b * 3 + sloc) * 2048 + ch;
    aq += wq.x * (in ? Yq[iy] : tq[it]);
    ak += wk.x * (in ? Yk[iy] : tk[it]);
    av += wv.x * (in ? Yv[iy] : tv[it]);
  }
  qb[idx] = aq * sigf(aq);
  kb[idx] = ak * sigf(ak) * 0.08838834764831845f;
  vb[idx] = av * sigf(av);
}

// copy last 3 rows (per batch) of chunk Yq/Yk/Yv into tails for the next chunk
__global__ void tail3_k(const float* __restrict__ Yq, const float* __restrict__ Yk,
                        const float* __restrict__ Yv, float* __restrict__ tq,
                        float* __restrict__ tk, float* __restrict__ tv, int SC) {
  int idx = blockIdx.x * 256 + threadIdx.x;  // < 4*3*2048 = 24576
  int ch = idx & 2047;
  int bt = idx >> 11;  // b*3 + t
  int t = bt % 3;
  int b = bt / 3;
  size_t src = ((size_t)(b * SC + SC - 3 + t) << 11) + ch;
  tq[idx] = Yq[src];
  tk[idx] = Yk[src];
  tv[idx] = Yv[src];
}

// ---------------------------------------------------------------------------
// delta-rule scan (chunked). Block = (b,h,16-row group); 512 blocks ->
// 2 blocks/CU (2 waves/SIMD). Thread owns 8 state elems; 16 lanes/row.
// Carried c = dot(S,k) reduced via all-DPP red16 (no LDS on the chain).
// Unroll-4 ring buffers give prefetch distance 4 steps with no rotation movs.
// End-of-chunk overreads (up to 4 rows) land in adjacent ws buffers - benign.
//   cf = beta*(c - v); St = a*St - cf*k; o = red(St.q); c' = red(St.k_next)
// ---------------------------------------------------------------------------
__global__ __launch_bounds__(256) void scan_k(const float* __restrict__ qf,
                                              const float* __restrict__ kf,
                                              const float* __restrict__ vf,
                                              const float* __restrict__ af,
                                              const float* __restrict__ betaf,
                                              float* __restrict__ of,
                                              float* __restrict__ state,
                                              int SC, int cOff, int init) {
  int blk = blockIdx.x;  // 0..511: (b<<7)|(h<<3)|rg
  int rg = blk & 7;
  int h = (blk >> 3) & 15;
  int b = blk >> 7;
  int t = threadIdx.x;
  int vrow = rg * 16 + (t >> 4);
  int l16 = t & 15;
  int e0 = l16 * 8;

  size_t stoff = ((size_t)((b * 16 + h) * 128 + vrow)) * 128 + e0;
  float St[8];
  if (init) {
#pragma unroll
    for (int i = 0; i < 8; ++i) St[i] = 0.f;
  } else {
    LD8(St, state + stoff);
  }

  const size_t step = NDC;
  size_t base = (size_t)(b * SC) * step + (size_t)h * DKC;
  const float* qp = qf + base + e0;
  const float* kp = kf + base + e0;
  const float* vp = vf + base + vrow;
  const float* ap = af + base + vrow;
  const float* bp = betaf + ((size_t)b * SEQ + cOff) * NHC + h;
  float* op = of + base + vrow;

  float kr[4][8], qr[4][8], vv[4], av[4], bv[4];
#pragma unroll
  for (int j = 0; j < 4; ++j) {
    LD8(kr[j], kp + (size_t)j * step);
    LD8(qr[j], qp + (size_t)j * step);
    vv[j] = vp[j * step];
    av[j] = ap[j * step];
    bv[j] = bp[j * NHC];
  }
  float c = red16(dot8(St, kr[0]));

  for (int s = 0; s < SC; s += 4) {
#pragma unroll
    for (int j = 0; j < 4; ++j) {
      float cf = bv[j] * (c - vv[j]);
      float at = av[j];
#pragma unroll
      for (int i = 0; i < 8; ++i) St[i] = at * St[i] - cf * kr[j][i];
      float ov = red16(dot8(St, qr[j]));
      if (l16 == 0) op[(size_t)j * step] = ov;
      // refill slot j with step s+4+j (prefetch distance 4)
      LD8(kr[j], kp + (size_t)(j + 4) * step);
      LD8(qr[j], qp + (size_t)(j + 4) * step);
      vv[j] = vp[(j + 4) * step];
      av[j] = ap[(j + 4) * step];
      bv[j] = bp[(j + 4) * NHC];
      // carried dot for step s+j+1: slot (j+1)&3 still holds k[s+j+1] for
      // j<3; for j==3, kr[0] was refilled with k[s+4] three sub-steps ago.
      c = red16(dot8(St, kr[(j + 1) & 3]));
    }
    qp += 4 * step; kp += 4 * step; vp += 4 * step; ap += 4 * step;
    bp += 4 * NHC; op += 4 * step;
  }

  ((float4*)(state + stoff))[0] = *(float4*)&St[0];
  ((float4*)(state + stoff))[1] = *(float4*)&St[4];
}

// ---------------------------------------------------------------------------
// per-(row,head) LayerNorm over DV=128 + ln affine + sigmoid-gate, write bf16
// ---------------------------------------------------------------------------
__global__ __launch_bounds__(256) void ln_gate_k(const float* __restrict__ o,
                                                 const float* __restrict__ g,
                                                 const float* __restrict__ lnw,
                                                 const float* __restrict__ lnb,
                                                 bf16_t* __restrict__ ofin) {
  int row = blockIdx.x;
  int wave = threadIdx.x >> 6, lane = threadIdx.x & 63;
  for (int h = wave; h < NHC; h += 4) {
    size_t off = (size_t)row * 2048 + (size_t)h * DVC + 2 * lane;
    float x0 = o[off], x1 = o[off + 1];
    float s1 = x0 + x1, s2 = x0 * x0 + x1 * x1;
#pragma unroll
    for (int sh = 32; sh; sh >>= 1) {
      s1 += __shfl_xor(s1, sh);
      s2 += __shfl_xor(s2, sh);
    }
    float mu = s1 * (1.f / 128.f);
    float var = s2 * (1.f / 128.f) - mu * mu;
    float inv = rsqrtf(fmaxf(var, 0.f) + 1e-5f);
    float y0 = ((x0 - mu) * inv * lnw[2 * lane] + lnb[2 * lane]) * g[off];
    float y1 = ((x1 - mu) * inv * lnw[2 * lane + 1] + lnb[2 * lane + 1]) * g[off + 1];
    ofin[off] = (bf16_t)y0;
    ofin[off + 1] = (bf16_t)y1;
  }
}

// ---------------------------------------------------------------------------
extern "C" void kernel_launch(void* const* d_in, const int* in_sizes, int n_in,
                              void* d_out, int out_size, void* d_ws, size_t ws_size,
                              hipStream_t stream) {
  const float* x   = (const float*)d_in[0];
  const float* Wq  = (const float*)d_in[1];
  const float* Wk  = (const float*)d_in[2];
  const float* Wv  = (const float*)d_in[3];
  const float* Wa  = (const float*)d_in[4];
  const float* ba  = (const float*)d_in[5];
  const float* Wb  = (const float*)d_in[6];
  const float* bb  = (const float*)d_in[7];
  const float* Wg  = (const float*)d_in[8];
  const float* Wo  = (const float*)d_in[9];
  const float* cqw = (const float*)d_in[10];
  const float* cqb = (const float*)d_in[11];
  const float* ckw = (const float*)d_in[12];
  const float* ckb = (const float*)d_in[13];
  const float* cvw = (const float*)d_in[14];
  const float* cvb = (const float*)d_in[15];
  const float* lnw = (const float*)d_in[16];
  const float* lnb = (const float*)d_in[17];
  float* outp = (float*)d_out;

  // --- pick chunking so the workspace fits ws_size ---
  const size_t WT    = (size_t)2048 * 2048 * sizeof(bf16_t);       // 8MB
  const size_t XB    = (size_t)MROWS * 2048 * sizeof(bf16_t);      // 32MB
  const size_t STATE = (size_t)4 * 16 * 128 * 128 * sizeof(float); // 4MB
  const size_t BETA  = (size_t)MROWS * NHC * sizeof(float);        // 512KB
  const size_t TAIL  = (size_t)4 * 3 * 2048 * sizeof(float);       // 96KB
  const size_t WBT   = (size_t)NHC * 2048 * sizeof(float);         // 128KB
  int nc = 16;
  {
    const int cands[5] = {1, 2, 4, 8, 16};
    for (int ci = 0; ci < 5; ++ci) {
      size_t CHc = ((size_t)MROWS / cands[ci]) * 2048 * sizeof(float);
      size_t need = 6 * WT + XB + 8 * CHc + STATE + BETA + 3 * TAIL + WBT + 4096;
      if (need <= ws_size) { nc = cands[ci]; break; }
    }
  }
  const int SC = SEQ / nc;
  int scShift = 0;
  while ((1 << scShift) < SC) ++scShift;
  const int Mc = MROWS / nc;  // chunk-local rows
  const size_t CH = (size_t)Mc * 2048 * sizeof(float);

  // --- workspace layout ---
  char* w = (char*)d_ws;
  bf16_t* Wtq = (bf16_t*)w; w += WT;
  bf16_t* Wtk = (bf16_t*)w; w += WT;
  bf16_t* Wtv = (bf16_t*)w; w += WT;
  bf16_t* Wta = (bf16_t*)w; w += WT;
  bf16_t* Wtg = (bf16_t*)w; w += WT;
  bf16_t* Wto = (bf16_t*)w; w += WT;
  bf16_t* xb  = (bf16_t*)w; w += XB;
  float* Yq = (float*)w; w += CH;
  float* Yk = (float*)w; w += CH;
  float* Yv = (float*)w; w += CH;
  float* Za = (float*)w; w += CH;   // sigmoid fused in GEMM epilogue -> a
  float* Zg = (float*)w; w += CH;   // sigmoid fused in GEMM epilogue -> g
  float* qb = (float*)w; w += CH;
  float* kb = (float*)w; w += CH;
  float* vb = (float*)w; w += CH;
  float* betab = (float*)w; w += BETA;
  float* state = (float*)w; w += STATE;
  float* tq = (float*)w; w += TAIL;
  float* tk = (float*)w; w += TAIL;
  float* tv = (float*)w; w += TAIL;
  float* Wbt = (float*)w; w += WBT;
  float* ob = Yq;              // alias: Yq dead after conv+tail of this chunk
  bf16_t* ofin = (bf16_t*)Yk;  // alias: Yk dead after conv+tail of this chunk

  dim3 tb(32, 8);
  dim3 tg(64, 64);
  transpose_k<<<tg, tb, 0, stream>>>(Wq, Wtq);
  transpose_k<<<tg, tb, 0, stream>>>(Wk, Wtk);
  transpose_k<<<tg, tb, 0, stream>>>(Wv, Wtv);
  transpose_k<<<tg, tb, 0, stream>>>(Wa, Wta);
  transpose_k<<<tg, tb, 0, stream>>>(Wg, Wtg);
  transpose_k<<<tg, tb, 0, stream>>>(Wo, Wto);
  f2b_k<<<MROWS * 2048 / (256 * 8), 256, 0, stream>>>(x, xb);
  wbt_k<<<(NHC * 2048) / 256, 256, 0, stream>>>(Wb, Wbt);

  beta_k<<<MROWS / 4, 256, 0, stream>>>(x, Wbt, bb, betab);

  dim3 gg(Mc / 128, 16);
  const int eblocks = (int)(((size_t)Mc * 2048) / 256);
  const int tblocks = (4 * 3 * 2048) / 256;

  for (int c = 0; c < nc; ++c) {
    const int cOff = c * SC;
    gemm_nt<float, 0><<<gg, 256, 0, stream>>>(xb, Wtq, Yq, nullptr, 2048, 2048, 1, 0, cOff, scShift);
    gemm_nt<float, 0><<<gg, 256, 0, stream>>>(xb, Wtk, Yk, nullptr, 2048, 2048, 1, 0, cOff, scShift);
    gemm_nt<float, 0><<<gg, 256, 0, stream>>>(xb, Wtv, Yv, nullptr, 2048, 2048, 1, 0, cOff, scShift);
    gemm_nt<float, 2><<<gg, 256, 0, stream>>>(xb, Wta, Za, ba, 2048, 2048, 1, 0, cOff, scShift);
    gemm_nt<float, 1><<<gg, 256, 0, stream>>>(xb, Wtg, Zg, nullptr, 2048, 2048, 1, 0, cOff, scShift);

    conv3_k<<<eblocks, 256, 0, stream>>>(Yq, Yk, Yv, tq, tk, tv, cqw, cqb, ckw, ckb,
                                         cvw, cvb, qb, kb, vb, cOff, scShift);
    if (c + 1 < nc)
      tail3_k<<<tblocks, 256, 0, stream>>>(Yq, Yk, Yv, tq, tk, tv, SC);

    scan_k<<<512, 256, 0, stream>>>(qb, kb, vb, Za, betab, ob, state, SC, cOff, c == 0 ? 1 : 0);

    ln_gate_k<<<Mc, 256, 0, stream>>>(ob, Zg, lnw, lnb, ofin);

    gemm_nt<float, 0><<<gg, 256, 0, stream>>>(ofin, Wto, outp, nullptr, 2048, 2048, 0, 1, cOff, scShift);
  }
}

// Round 2
// 1994.276 us; speedup vs baseline: 1.4919x; 1.2838x over previous
//
#include <hip/hip_runtime.h>

// Problem constants
#define BATCH 4
#define SEQ   2048
#define HIDC  2048
#define NHC   16
#define DKC   128
#define DVC   128
#define MROWS (BATCH * SEQ)   // 8192
#define NDC   2048            // NH*DK = NH*DV

typedef __bf16 bf16_t;
typedef __bf16 bf16x8 __attribute__((ext_vector_type(8)));
typedef float  floatx4 __attribute__((ext_vector_type(4)));

__device__ __forceinline__ float sigf(float z) { return 1.f / (1.f + __expf(-z)); }

// async global->LDS, 16B per lane. LDS dest is wave-uniform base + lane*16.
#define GLL16(g, l)                                                              \
  __builtin_amdgcn_global_load_lds(                                              \
      (const __attribute__((address_space(1))) void*)(g),                        \
      (__attribute__((address_space(3))) void*)(l), 16, 0, 0)

// 16-lane sum reduce, entirely on the VALU pipe (DPP, no LDS).
__device__ __forceinline__ float red16(float x) {
  int a;
  a = __float_as_int(x);
  x += __int_as_float(__builtin_amdgcn_update_dpp(a, a, 0xB1, 0xF, 0xF, true));   // xor 1
  a = __float_as_int(x);
  x += __int_as_float(__builtin_amdgcn_update_dpp(a, a, 0x4E, 0xF, 0xF, true));   // xor 2
  a = __float_as_int(x);
  x += __int_as_float(__builtin_amdgcn_update_dpp(a, a, 0x141, 0xF, 0xF, true));  // row_half_mirror
  a = __float_as_int(x);
  x += __int_as_float(__builtin_amdgcn_update_dpp(a, a, 0x140, 0xF, 0xF, true));  // row_mirror
  return x;
}

__device__ __forceinline__ float dot8(const float* a, const float* b) {
  float d0 = 0.f, d1 = 0.f;
#pragma unroll
  for (int i = 0; i < 4; ++i) {
    d0 += a[i] * b[i];
    d1 += a[4 + i] * b[4 + i];
  }
  return d0 + d1;
}

#define LD8(dst, ptr)                                \
  {                                                  \
    *(float4*)&dst[0] = ((const float4*)(ptr))[0];   \
    *(float4*)&dst[4] = ((const float4*)(ptr))[1];   \
  }

// ---------------------------------------------------------------------------
// fp32 -> bf16 convert (8 elems/thread)
// ---------------------------------------------------------------------------
__global__ __launch_bounds__(256) void f2b_k(const float* __restrict__ src,
                                             bf16_t* __restrict__ dst) {
  size_t i = ((size_t)blockIdx.x * 256 + threadIdx.x) * 8;
  float4 a = *(const float4*)(src + i);
  float4 b = *(const float4*)(src + i + 4);
  bf16_t tmp[8] = {(bf16_t)a.x, (bf16_t)a.y, (bf16_t)a.z, (bf16_t)a.w,
                   (bf16_t)b.x, (bf16_t)b.y, (bf16_t)b.z, (bf16_t)b.w};
  *(bf16x8*)(dst + i) = *(bf16x8*)tmp;
}

// ---------------------------------------------------------------------------
// Transpose+convert 2048x2048: Wt[n][k] = bf16(W[k][n]), W fp32
// ---------------------------------------------------------------------------
__global__ __launch_bounds__(256) void transpose_k(const float* __restrict__ W,
                                                   bf16_t* __restrict__ Wt) {
  __shared__ float tile[32][33];
  int kb = blockIdx.x * 32, nb = blockIdx.y * 32;
  int tx = threadIdx.x, ty = threadIdx.y;  // (32,8)
#pragma unroll
  for (int r = 0; r < 4; ++r)
    tile[ty + 8 * r][tx] = W[(size_t)(kb + ty + 8 * r) * 2048 + nb + tx];
  __syncthreads();
#pragma unroll
  for (int r = 0; r < 4; ++r)
    Wt[(size_t)(nb + ty + 8 * r) * 2048 + kb + tx] = (bf16_t)tile[tx][ty + 8 * r];
}

// ---------------------------------------------------------------------------
// Transpose Wb 2048x16 -> Wbt 16x2048 (fp32), one-time 128KB shuffle.
// ---------------------------------------------------------------------------
__global__ __launch_bounds__(256) void wbt_k(const float* __restrict__ Wb,
                                             float* __restrict__ Wbt) {
  int idx = blockIdx.x * 256 + threadIdx.x;  // < 16*2048
  int n = idx >> 11;
  int j = idx & 2047;
  Wbt[idx] = Wb[(size_t)j * NHC + n];
}

// ---------------------------------------------------------------------------
// m97-structure bf16 MFMA GEMM (NT): 128x128 tile, BK=32, 4 waves (64x64 each,
// 4x4 of 16x16x32 mfma). global_load_lds width-16 into LINEAR LDS [128][32];
// each wave stages a contiguous 1KB chunk (lane l -> byte l*16). Fragment
// ds_read_b128: for fixed i, 64 lanes cover a contiguous 1KB -> conflict-free.
// MODE 0: fused 5-segment projection GEMM. A rows chunk-mapped (amap); B is
//         the stacked [10240][2048] Wtq|Wtk|Wtv|Wta|Wtg; segment = n0>>11
//         picks output buffer + epilogue (0,1,2=plain; 3=sig+bias; 4=sig).
//         C rows are chunk-local.
// MODE 1: output GEMM. A rows local (ofin), C rows chunk-mapped (cmap), N=2048.
// ---------------------------------------------------------------------------
template <int MODE>
__global__ __launch_bounds__(256) void gemm97(const bf16_t* __restrict__ A,
                                              const bf16_t* __restrict__ Bt,
                                              float* __restrict__ C0,
                                              float* __restrict__ C1,
                                              float* __restrict__ C2,
                                              float* __restrict__ C3,
                                              float* __restrict__ C4,
                                              const float* __restrict__ bias,
                                              int cOff, int scShift) {
  __shared__ bf16_t As[128 * 32];
  __shared__ bf16_t Bs[128 * 32];
  const int tid = threadIdx.x;
  const int wave = tid >> 6;
  const int lane = tid & 63;
  const int m0 = blockIdx.x * 128;
  const int n0 = blockIdx.y * 128;
  const int K = 2048;
  const int scMask = (1 << scShift) - 1;
  const int ga = (MODE == 0) ? (((m0 >> scShift) << 11) + cOff + (m0 & scMask)) : m0;
  const int gc = (MODE == 1) ? (((m0 >> scShift) << 11) + cOff + (m0 & scMask)) : m0;

  const int wm = (wave >> 1) * 64;
  const int wn = (wave & 1) * 64;
  const int qd = lane >> 4;   // quad 0..3
  const int l16 = lane & 15;

  // staging geometry: wave w, round r covers rows r*64 + 16w .. +16 (1KB)
  const int srow = lane >> 2;          // 0..15 row-within-chunk
  const int skel = (lane & 3) * 8;     // element offset within 32-elem row

  const bf16_t* agA0 = A + (size_t)(ga + 16 * wave + srow) * K + skel;
  const bf16_t* agA1 = agA0 + (size_t)64 * K;
  const bf16_t* bgB0 = Bt + (size_t)(n0 + 16 * wave + srow) * K + skel;
  const bf16_t* bgB1 = bgB0 + (size_t)64 * K;
  bf16_t* lA0 = &As[(16 * wave) * 32];
  bf16_t* lA1 = &As[(64 + 16 * wave) * 32];
  bf16_t* lB0 = &Bs[(16 * wave) * 32];
  bf16_t* lB1 = &Bs[(64 + 16 * wave) * 32];

  // fragment read pointers (constant across K loop)
  const bf16_t* pa[4];
  const bf16_t* pb[4];
#pragma unroll
  for (int i = 0; i < 4; ++i) {
    pa[i] = &As[(wm + 16 * i + l16) * 32 + qd * 8];
    pb[i] = &Bs[(wn + 16 * i + l16) * 32 + qd * 8];
  }

  const floatx4 fzero = {0.f, 0.f, 0.f, 0.f};
  floatx4 acc[4][4];
#pragma unroll
  for (int i = 0; i < 4; ++i)
#pragma unroll
    for (int j = 0; j < 4; ++j) acc[i][j] = fzero;

  for (int k0 = 0; k0 < K; k0 += 32) {
    GLL16(agA0 + k0, lA0);
    GLL16(agA1 + k0, lA1);
    GLL16(bgB0 + k0, lB0);
    GLL16(bgB1 + k0, lB1);
    __syncthreads();
    bf16x8 afr[4], bfr[4];
#pragma unroll
    for (int i = 0; i < 4; ++i) afr[i] = *(const bf16x8*)pa[i];
#pragma unroll
    for (int j = 0; j < 4; ++j) bfr[j] = *(const bf16x8*)pb[j];
#pragma unroll
    for (int i = 0; i < 4; ++i)
#pragma unroll
      for (int j = 0; j < 4; ++j)
        acc[i][j] = __builtin_amdgcn_mfma_f32_16x16x32_bf16(afr[i], bfr[j], acc[i][j], 0, 0, 0);
    __syncthreads();
  }

  // C/D layout: col(N) = lane&15, row(M) = (lane>>4)*4 + reg  [measured m89]
  if (MODE == 0) {
    const int sid = n0 >> 11;
    float* Cp = (sid == 0) ? C0 : (sid == 1) ? C1 : (sid == 2) ? C2 : (sid == 3) ? C3 : C4;
    const int nb = n0 & 2047;
#pragma unroll
    for (int i = 0; i < 4; ++i)
#pragma unroll
      for (int j = 0; j < 4; ++j)
#pragma unroll
        for (int r = 0; r < 4; ++r) {
          int mm = m0 + wm + 16 * i + qd * 4 + r;
          int nn = nb + wn + 16 * j + l16;
          float val = acc[i][j][r];
          if (sid == 3) val = sigf(val + bias[nn]);
          else if (sid == 4) val = sigf(val);
          Cp[(size_t)mm * 2048 + nn] = val;
        }
  } else {
#pragma unroll
    for (int i = 0; i < 4; ++i)
#pragma unroll
      for (int j = 0; j < 4; ++j)
#pragma unroll
        for (int r = 0; r < 4; ++r) {
          int mm = gc + wm + 16 * i + qd * 4 + r;
          int nn = n0 + wn + 16 * j + l16;
          C0[(size_t)mm * 2048 + nn] = acc[i][j][r];
        }
  }
}

// ---------------------------------------------------------------------------
// beta = sigmoid(x @ Wb + bb)   x:[8192,2048] fp32, Wbt:[16,2048] fp32.
// ---------------------------------------------------------------------------
__global__ __launch_bounds__(256) void beta_k(const float* __restrict__ x,
                                              const float* __restrict__ Wbt,
                                              const float* __restrict__ bb,
                                              float* __restrict__ beta) {
  __shared__ float xs[4][HIDC];
  const int row0 = blockIdx.x * 4;
  for (int i = threadIdx.x; i < 4 * (HIDC / 4); i += 256) {
    int r = i >> 9;          // /512
    int j = i & 511;
    ((float4*)xs[r])[j] = ((const float4*)(x + (size_t)(row0 + r) * HIDC))[j];
  }
  __syncthreads();
  const int wave = threadIdx.x >> 6, lane = threadIdx.x & 63;
#pragma unroll
  for (int nb = 0; nb < 4; ++nb) {
    const int n = wave + nb * 4;
    float acc0 = 0.f, acc1 = 0.f, acc2 = 0.f, acc3 = 0.f;
    const float4* wrow = (const float4*)(Wbt + (size_t)n * HIDC);
    for (int j = lane; j < HIDC / 4; j += 64) {
      float4 wv = wrow[j];
      float4 x0 = ((const float4*)xs[0])[j];
      float4 x1 = ((const float4*)xs[1])[j];
      float4 x2 = ((const float4*)xs[2])[j];
      float4 x3 = ((const float4*)xs[3])[j];
      acc0 += wv.x * x0.x + wv.y * x0.y + wv.z * x0.z + wv.w * x0.w;
      acc1 += wv.x * x1.x + wv.y * x1.y + wv.z * x1.z + wv.w * x1.w;
      acc2 += wv.x * x2.x + wv.y * x2.y + wv.z * x2.z + wv.w * x2.w;
      acc3 += wv.x * x3.x + wv.y * x3.y + wv.z * x3.z + wv.w * x3.w;
    }
    float accs[4] = {acc0, acc1, acc2, acc3};
#pragma unroll
    for (int r = 0; r < 4; ++r) {
      float s = accs[r];
#pragma unroll
      for (int off = 32; off; off >>= 1) s += __shfl_xor(s, off);
      if (lane == 0) beta[(size_t)(row0 + r) * NHC + n] = sigf(s + bb[n]);
    }
  }
}

// ---------------------------------------------------------------------------
// fused 3x causal depthwise conv (K=4) + bias + SiLU (*scale for k).
// ---------------------------------------------------------------------------
__global__ void conv3_k(const float* __restrict__ Yq, const float* __restrict__ Yk,
                        const float* __restrict__ Yv,
                        const float* __restrict__ tq, const float* __restrict__ tk,
                        const float* __restrict__ tv,
                        const float* __restrict__ cqw, const float* __restrict__ cqb,
                        const float* __restrict__ ckw, const float* __restrict__ ckb,
                        const float* __restrict__ cvw, const float* __restrict__ cvb,
                        float* __restrict__ qb, float* __restrict__ kb,
                        float* __restrict__ vb, int cOff, int scShift) {
  size_t idx = (size_t)blockIdx.x * blockDim.x + threadIdx.x;
  int ch = (int)(idx & 2047);
  int mloc = (int)(idx >> 11);
  int sloc = mloc & ((1 << scShift) - 1);
  int b = mloc >> scShift;
  int sg = cOff + sloc;
  float4 wq = *(const float4*)(cqw + ch * 4);  // .x=w0 .y=w1 .z=w2 .w=w3
  float4 wk = *(const float4*)(ckw + ch * 4);
  float4 wv = *(const float4*)(cvw + ch * 4);
  float aq = cqb[ch] + wq.w * Yq[idx];
  float ak = ckb[ch] + wk.w * Yk[idx];
  float av = cvb[ch] + wv.w * Yv[idx];
  if (sg >= 1) {
    bool in = sloc >= 1;
    size_t iy = idx - 2048;
    size_t it = (size_t)(b * 3 + 2 + sloc) * 2048 + ch;
    aq += wq.z * (in ? Yq[iy] : tq[it]);
    ak += wk.z * (in ? Yk[iy] : tk[it]);
    av += wv.z * (in ? Yv[iy] : tv[it]);
  }
  if (sg >= 2) {
    bool in = sloc >= 2;
    size_t iy = idx - 2 * 2048;
    size_t it = (size_t)(b * 3 + 1 + sloc) * 2048 + ch;
    aq += wq.y * (in ? Yq[iy] : tq[it]);
    ak += wk.y * (in ? Yk[iy] : tk[it]);
    av += wv.y * (in ? Yv[iy] : tv[it]);
  }
  if (sg >= 3) {
    bool in = sloc >= 3;
    size_t iy = idx - 3 * 2048;
    size_t it = (size_t)(b * 3 + sloc) * 2048 + ch;
    aq += wq.x * (in ? Yq[iy] : tq[it]);
    ak += wk.x * (in ? Yk[iy] : tk[it]);
    av += wv.x * (in ? Yv[iy] : tv[it]);
  }
  qb[idx] = aq * sigf(aq);
  kb[idx] = ak * sigf(ak) * 0.08838834764831845f;
  vb[idx] = av * sigf(av);
}

// copy last 3 rows (per batch) of chunk Yq/Yk/Yv into tails for the next chunk
__global__ void tail3_k(const float* __restrict__ Yq, const float* __restrict__ Yk,
                        const float* __restrict__ Yv, float* __restrict__ tq,
                        float* __restrict__ tk, float* __restrict__ tv, int SC) {
  int idx = blockIdx.x * 256 + threadIdx.x;  // < 4*3*2048 = 24576
  int ch = idx & 2047;
  int bt = idx >> 11;  // b*3 + t
  int t = bt % 3;
  int b = bt / 3;
  size_t src = ((size_t)(b * SC + SC - 3 + t) << 11) + ch;
  tq[idx] = Yq[src];
  tk[idx] = Yk[src];
  tv[idx] = Yv[src];
}

// ---------------------------------------------------------------------------
// delta-rule scan (chunked). Block = (b,h,16-row group); 512 blocks.
// ---------------------------------------------------------------------------
__global__ __launch_bounds__(256) void scan_k(const float* __restrict__ qf,
                                              const float* __restrict__ kf,
                                              const float* __restrict__ vf,
                                              const float* __restrict__ af,
                                              const float* __restrict__ betaf,
                                              float* __restrict__ of,
                                              float* __restrict__ state,
                                              int SC, int cOff, int init) {
  int blk = blockIdx.x;  // 0..511: (b<<7)|(h<<3)|rg
  int rg = blk & 7;
  int h = (blk >> 3) & 15;
  int b = blk >> 7;
  int t = threadIdx.x;
  int vrow = rg * 16 + (t >> 4);
  int l16 = t & 15;
  int e0 = l16 * 8;

  size_t stoff = ((size_t)((b * 16 + h) * 128 + vrow)) * 128 + e0;
  float St[8];
  if (init) {
#pragma unroll
    for (int i = 0; i < 8; ++i) St[i] = 0.f;
  } else {
    LD8(St, state + stoff);
  }

  const size_t step = NDC;
  size_t base = (size_t)(b * SC) * step + (size_t)h * DKC;
  const float* qp = qf + base + e0;
  const float* kp = kf + base + e0;
  const float* vp = vf + base + vrow;
  const float* ap = af + base + vrow;
  const float* bp = betaf + ((size_t)b * SEQ + cOff) * NHC + h;
  float* op = of + base + vrow;

  float kr[4][8], qr[4][8], vv[4], av[4], bv[4];
#pragma unroll
  for (int j = 0; j < 4; ++j) {
    LD8(kr[j], kp + (size_t)j * step);
    LD8(qr[j], qp + (size_t)j * step);
    vv[j] = vp[j * step];
    av[j] = ap[j * step];
    bv[j] = bp[j * NHC];
  }
  float c = red16(dot8(St, kr[0]));

  for (int s = 0; s < SC; s += 4) {
#pragma unroll
    for (int j = 0; j < 4; ++j) {
      float cf = bv[j] * (c - vv[j]);
      float at = av[j];
#pragma unroll
      for (int i = 0; i < 8; ++i) St[i] = at * St[i] - cf * kr[j][i];
      float ov = red16(dot8(St, qr[j]));
      if (l16 == 0) op[(size_t)j * step] = ov;
      // refill slot j with step s+4+j (prefetch distance 4)
      LD8(kr[j], kp + (size_t)(j + 4) * step);
      LD8(qr[j], qp + (size_t)(j + 4) * step);
      vv[j] = vp[(j + 4) * step];
      av[j] = ap[(j + 4) * step];
      bv[j] = bp[(j + 4) * NHC];
      c = red16(dot8(St, kr[(j + 1) & 3]));
    }
    qp += 4 * step; kp += 4 * step; vp += 4 * step; ap += 4 * step;
    bp += 4 * NHC; op += 4 * step;
  }

  ((float4*)(state + stoff))[0] = *(float4*)&St[0];
  ((float4*)(state + stoff))[1] = *(float4*)&St[4];
}

// ---------------------------------------------------------------------------
// per-(row,head) LayerNorm over DV=128 + ln affine + sigmoid-gate, write bf16
// ---------------------------------------------------------------------------
__global__ __launch_bounds__(256) void ln_gate_k(const float* __restrict__ o,
                                                 const float* __restrict__ g,
                                                 const float* __restrict__ lnw,
                                                 const float* __restrict__ lnb,
                                                 bf16_t* __restrict__ ofin) {
  int row = blockIdx.x;
  int wave = threadIdx.x >> 6, lane = threadIdx.x & 63;
  for (int h = wave; h < NHC; h += 4) {
    size_t off = (size_t)row * 2048 + (size_t)h * DVC + 2 * lane;
    float x0 = o[off], x1 = o[off + 1];
    float s1 = x0 + x1, s2 = x0 * x0 + x1 * x1;
#pragma unroll
    for (int sh = 32; sh; sh >>= 1) {
      s1 += __shfl_xor(s1, sh);
      s2 += __shfl_xor(s2, sh);
    }
    float mu = s1 * (1.f / 128.f);
    float var = s2 * (1.f / 128.f) - mu * mu;
    float inv = rsqrtf(fmaxf(var, 0.f) + 1e-5f);
    float y0 = ((x0 - mu) * inv * lnw[2 * lane] + lnb[2 * lane]) * g[off];
    float y1 = ((x1 - mu) * inv * lnw[2 * lane + 1] + lnb[2 * lane + 1]) * g[off + 1];
    ofin[off] = (bf16_t)y0;
    ofin[off + 1] = (bf16_t)y1;
  }
}

// ---------------------------------------------------------------------------
extern "C" void kernel_launch(void* const* d_in, const int* in_sizes, int n_in,
                              void* d_out, int out_size, void* d_ws, size_t ws_size,
                              hipStream_t stream) {
  const float* x   = (const float*)d_in[0];
  const float* Wq  = (const float*)d_in[1];
  const float* Wk  = (const float*)d_in[2];
  const float* Wv  = (const float*)d_in[3];
  const float* Wa  = (const float*)d_in[4];
  const float* ba  = (const float*)d_in[5];
  const float* Wb  = (const float*)d_in[6];
  const float* bb  = (const float*)d_in[7];
  const float* Wg  = (const float*)d_in[8];
  const float* Wo  = (const float*)d_in[9];
  const float* cqw = (const float*)d_in[10];
  const float* cqb = (const float*)d_in[11];
  const float* ckw = (const float*)d_in[12];
  const float* ckb = (const float*)d_in[13];
  const float* cvw = (const float*)d_in[14];
  const float* cvb = (const float*)d_in[15];
  const float* lnw = (const float*)d_in[16];
  const float* lnb = (const float*)d_in[17];
  float* outp = (float*)d_out;

  // --- pick chunking so the workspace fits ws_size ---
  const size_t WT    = (size_t)2048 * 2048 * sizeof(bf16_t);       // 8MB
  const size_t XB    = (size_t)MROWS * 2048 * sizeof(bf16_t);      // 32MB
  const size_t STATE = (size_t)4 * 16 * 128 * 128 * sizeof(float); // 4MB
  const size_t BETA  = (size_t)MROWS * NHC * sizeof(float);        // 512KB
  const size_t TAIL  = (size_t)4 * 3 * 2048 * sizeof(float);       // 96KB
  const size_t WBT   = (size_t)NHC * 2048 * sizeof(float);         // 128KB
  int nc = 16;
  {
    const int cands[5] = {1, 2, 4, 8, 16};
    for (int ci = 0; ci < 5; ++ci) {
      size_t CHc = ((size_t)MROWS / cands[ci]) * 2048 * sizeof(float);
      size_t need = 6 * WT + XB + 8 * CHc + STATE + BETA + 3 * TAIL + WBT + 4096;
      if (need <= ws_size) { nc = cands[ci]; break; }
    }
  }
  const int SC = SEQ / nc;
  int scShift = 0;
  while ((1 << scShift) < SC) ++scShift;
  const int Mc = MROWS / nc;  // chunk-local rows
  const size_t CH = (size_t)Mc * 2048 * sizeof(float);

  // --- workspace layout (Wtq..Wtg MUST stay contiguous: stacked-B GEMM) ---
  char* w = (char*)d_ws;
  bf16_t* Wtq = (bf16_t*)w; w += WT;
  bf16_t* Wtk = (bf16_t*)w; w += WT;
  bf16_t* Wtv = (bf16_t*)w; w += WT;
  bf16_t* Wta = (bf16_t*)w; w += WT;
  bf16_t* Wtg = (bf16_t*)w; w += WT;
  bf16_t* Wto = (bf16_t*)w; w += WT;
  bf16_t* xb  = (bf16_t*)w; w += XB;
  float* Yq = (float*)w; w += CH;
  float* Yk = (float*)w; w += CH;
  float* Yv = (float*)w; w += CH;
  float* Za = (float*)w; w += CH;   // sigmoid fused in GEMM epilogue -> a
  float* Zg = (float*)w; w += CH;   // sigmoid fused in GEMM epilogue -> g
  float* qb = (float*)w; w += CH;
  float* kb = (float*)w; w += CH;
  float* vb = (float*)w; w += CH;
  float* betab = (float*)w; w += BETA;
  float* state = (float*)w; w += STATE;
  float* tq = (float*)w; w += TAIL;
  float* tk = (float*)w; w += TAIL;
  float* tv = (float*)w; w += TAIL;
  float* Wbt = (float*)w; w += WBT;
  float* ob = Yq;              // alias: Yq dead after conv+tail of this chunk
  bf16_t* ofin = (bf16_t*)Yk;  // alias: Yk dead after conv+tail of this chunk

  dim3 tb(32, 8);
  dim3 tg(64, 64);
  transpose_k<<<tg, tb, 0, stream>>>(Wq, Wtq);
  transpose_k<<<tg, tb, 0, stream>>>(Wk, Wtk);
  transpose_k<<<tg, tb, 0, stream>>>(Wv, Wtv);
  transpose_k<<<tg, tb, 0, stream>>>(Wa, Wta);
  transpose_k<<<tg, tb, 0, stream>>>(Wg, Wtg);
  transpose_k<<<tg, tb, 0, stream>>>(Wo, Wto);
  f2b_k<<<MROWS * 2048 / (256 * 8), 256, 0, stream>>>(x, xb);
  wbt_k<<<(NHC * 2048) / 256, 256, 0, stream>>>(Wb, Wbt);

  beta_k<<<MROWS / 4, 256, 0, stream>>>(x, Wbt, bb, betab);

  dim3 gg5(Mc / 128, 80);   // fused q,k,v,a,g projections (stacked B)
  dim3 ggo(Mc / 128, 16);   // output GEMM
  const int eblocks = (int)(((size_t)Mc * 2048) / 256);
  const int tblocks = (4 * 3 * 2048) / 256;

  for (int c = 0; c < nc; ++c) {
    const int cOff = c * SC;
    gemm97<0><<<gg5, 256, 0, stream>>>(xb, Wtq, Yq, Yk, Yv, Za, Zg, ba, cOff, scShift);

    conv3_k<<<eblocks, 256, 0, stream>>>(Yq, Yk, Yv, tq, tk, tv, cqw, cqb, ckw, ckb,
                                         cvw, cvb, qb, kb, vb, cOff, scShift);
    if (c + 1 < nc)
      tail3_k<<<tblocks, 256, 0, stream>>>(Yq, Yk, Yv, tq, tk, tv, SC);

    scan_k<<<512, 256, 0, stream>>>(qb, kb, vb, Za, betab, ob, state, SC, cOff, c == 0 ? 1 : 0);

    ln_gate_k<<<Mc, 256, 0, stream>>>(ob, Zg, lnw, lnb, ofin);

    gemm97<1><<<ggo, 256, 0, stream>>>(ofin, Wto, outp, nullptr, nullptr, nullptr, nullptr,
                                       nullptr, cOff, scShift);
  }
}